// Round 3
// baseline (18562.526 us; speedup 1.0000x reference)
//
#include <hip/hip_runtime.h>

// Fused tanh-RNN forward: x[B,784] -> softmax(FC(h_T)), B=65536, T=28, I=28, H=64, C=10.
// Round 2 (resubmit; round-2 bench never acquired a GPU): fix the scratch-spill
// catastrophe from round 1 (VGPR=72, 426MB scratch writes). State lives in f32x4
// ext-vectors (16 regs of 4) with constant indices after forced unrolls -> SROA
// promotes (m93 pattern). Weights staged transposed in LDS so the j-dimension is
// contiguous: each (i or k) step is one broadcast ds_read_b128 per 4 outputs.
// x rows double-buffered in registers to hide HBM latency (1 wave/SIMD).

namespace {

constexpr int T = 28;
constexpr int I = 28;
constexpr int H = 64;
constexpr int C = 10;
constexpr int HQ = H / 4;   // 16
constexpr int IQ = I / 4;   // 7

typedef float f4 __attribute__((ext_vector_type(4)));

__device__ __forceinline__ float fast_tanh(float xx) {
    // tanh(x) = 1 - 2/(exp(2x)+1); saturates correctly at +-1.
    float e = __expf(2.0f * xx);
    float r = __builtin_amdgcn_rcpf(e + 1.0f);
    return fmaf(-2.0f, r, 1.0f);
}

__global__ __launch_bounds__(256, 1) void rnn_fused(
    const float* __restrict__ x,
    const float* __restrict__ W_ih,   // [H][I] row-major
    const float* __restrict__ W_hh,   // [H][H] row-major
    const float* __restrict__ b_ih,   // [H]
    const float* __restrict__ b_hh,   // [H]
    const float* __restrict__ fc_w,   // [C][H] row-major
    const float* __restrict__ fc_b,   // [C]
    float* __restrict__ out,          // [B][C]
    int nB)
{
    // Transposed weight tiles: j (output unit) contiguous -> f4 along j.
    __shared__ f4 sWihT[I][HQ];   // sWihT[i][jq][e] = W_ih[(jq*4+e)][i]
    __shared__ f4 sWhhT[H][HQ];   // sWhhT[k][jq][e] = W_hh[(jq*4+e)][k]
    __shared__ f4 sB[HQ];         // b_ih + b_hh
    __shared__ f4 sFc[C][HQ];     // fc_w row-major
    __shared__ float sFcB[C];

    const int tid = threadIdx.x;
    {
        float* wih = reinterpret_cast<float*>(sWihT);
        for (int idx = tid; idx < H * I; idx += 256) {
            const int j = idx / I, i = idx - j * I;
            wih[i * H + j] = W_ih[idx];
        }
        float* whh = reinterpret_cast<float*>(sWhhT);
        for (int idx = tid; idx < H * H; idx += 256) {
            const int j = idx >> 6, k = idx & (H - 1);
            whh[k * H + j] = W_hh[idx];
        }
        float* fcl = reinterpret_cast<float*>(sFc);
        for (int idx = tid; idx < C * H; idx += 256) fcl[idx] = fc_w[idx];
        if (tid < H) reinterpret_cast<float*>(sB)[tid] = b_ih[tid] + b_hh[tid];
        if (tid < C) sFcB[tid] = fc_b[tid];
    }
    __syncthreads();

    const int s = blockIdx.x * blockDim.x + tid;
    if (s >= nB) return;   // nB = 65536 = grid exactly; sync already done

    const f4* __restrict__ xr = reinterpret_cast<const f4*>(x + (size_t)s * (T * I));

    f4 h[HQ];
    f4 xc[IQ], xn[IQ];

    #pragma unroll 7
    for (int q = 0; q < IQ; ++q) xc[q] = xr[q];            // x_0
    #pragma unroll 7
    for (int q = 0; q < IQ; ++q) xn[q] = xr[IQ + q];       // prefetch x_1

    // ---- t = 0: h = tanh(x_0 @ W_ih^T + b); h0 == 0 so no recurrent term ----
    {
        f4 acc[HQ];
        #pragma unroll 16
        for (int jq = 0; jq < HQ; ++jq) acc[jq] = sB[jq];
        #pragma unroll 28
        for (int i = 0; i < I; ++i) {
            const float xi = xc[i >> 2][i & 3];
            const f4 xs = {xi, xi, xi, xi};
            #pragma unroll 16
            for (int jq = 0; jq < HQ; ++jq)
                acc[jq] = __builtin_elementwise_fma(xs, sWihT[i][jq], acc[jq]);
        }
        #pragma unroll 16
        for (int jq = 0; jq < HQ; ++jq) {
            f4 r;
            #pragma unroll 4
            for (int e = 0; e < 4; ++e) r[e] = fast_tanh(acc[jq][e]);
            h[jq] = r;
        }
    }

    // ---- t = 1 .. T-1 ----
    for (int t = 1; t < T; ++t) {
        #pragma unroll 7
        for (int q = 0; q < IQ; ++q) xc[q] = xn[q];
        const int tn = (t + 1 < T) ? t + 1 : t;             // clamped prefetch
        #pragma unroll 7
        for (int q = 0; q < IQ; ++q) xn[q] = xr[tn * IQ + q];

        f4 acc[HQ];
        #pragma unroll 16
        for (int jq = 0; jq < HQ; ++jq) acc[jq] = sB[jq];
        #pragma unroll 28
        for (int i = 0; i < I; ++i) {
            const float xi = xc[i >> 2][i & 3];
            const f4 xs = {xi, xi, xi, xi};
            #pragma unroll 16
            for (int jq = 0; jq < HQ; ++jq)
                acc[jq] = __builtin_elementwise_fma(xs, sWihT[i][jq], acc[jq]);
        }
        #pragma unroll 64
        for (int k = 0; k < H; ++k) {
            const float hk = h[k >> 2][k & 3];
            const f4 hs = {hk, hk, hk, hk};
            #pragma unroll 16
            for (int jq = 0; jq < HQ; ++jq)
                acc[jq] = __builtin_elementwise_fma(hs, sWhhT[k][jq], acc[jq]);
        }
        #pragma unroll 16
        for (int jq = 0; jq < HQ; ++jq) {
            f4 r;
            #pragma unroll 4
            for (int e = 0; e < 4; ++e) r[e] = fast_tanh(acc[jq][e]);
            h[jq] = r;
        }
    }

    // ---- FC + softmax ----
    float logits[C];
    #pragma unroll 10
    for (int c = 0; c < C; ++c) {
        f4 d = {0.0f, 0.0f, 0.0f, 0.0f};
        #pragma unroll 16
        for (int jq = 0; jq < HQ; ++jq)
            d = __builtin_elementwise_fma(h[jq], sFc[c][jq], d);
        logits[c] = sFcB[c] + ((d[0] + d[1]) + (d[2] + d[3]));
    }
    float m = logits[0];
    #pragma unroll 9
    for (int c = 1; c < C; ++c) m = fmaxf(m, logits[c]);
    float sum = 0.0f;
    #pragma unroll 10
    for (int c = 0; c < C; ++c) {
        const float e = __expf(logits[c] - m);
        logits[c] = e;
        sum += e;
    }
    float r = __builtin_amdgcn_rcpf(sum);
    r = r * (2.0f - sum * r);               // one Newton step
    float2* o2 = reinterpret_cast<float2*>(out + (size_t)s * C);
    #pragma unroll 5
    for (int p = 0; p < 5; ++p) {
        float2 v;
        v.x = logits[2 * p] * r;
        v.y = logits[2 * p + 1] * r;
        o2[p] = v;
    }
}

} // namespace

extern "C" void kernel_launch(void* const* d_in, const int* in_sizes, int n_in,
                              void* d_out, int out_size, void* d_ws, size_t ws_size,
                              hipStream_t stream) {
    const float* x    = (const float*)d_in[0];
    const float* W_ih = (const float*)d_in[1];
    const float* W_hh = (const float*)d_in[2];
    const float* b_ih = (const float*)d_in[3];
    const float* b_hh = (const float*)d_in[4];
    const float* fc_w = (const float*)d_in[5];
    const float* fc_b = (const float*)d_in[6];
    float* out = (float*)d_out;

    const int nB = in_sizes[0] / (T * I);   // 65536
    const int block = 256;
    const int grid = (nB + block - 1) / block;
    rnn_fused<<<grid, block, 0, stream>>>(x, W_ih, W_hh, b_ih, b_hh, fc_w, fc_b, out, nB);
}

// Round 4
// 897.068 us; speedup vs baseline: 20.6924x; 20.6924x over previous
//
#include <hip/hip_runtime.h>

// Fused tanh-RNN: x[B,784] -> softmax(FC(h_T)), B=65536, T=28, I=28, H=64, C=10.
// Round 4: mapping A (1 thread = 1 sample) with WEIGHTS VIA SCALAR LOADS.
// Key lesson from rounds 1-3:
//   r1: weights s_load'd (SGPR=112, VGPR=72) but h/hn not promoted -> scratch.
//   r3: arrays promoted BUT weights via LDS -> 1472 f4 ds_reads/step inflate
//       VGPR pressure past 256 -> 19.7GB scratch traffic.
// Fix: weights are wave-uniform -> compiler emits s_load_dwordx16 + v_fmac v,s,v
// (zero VGPR cost, zero DS traffic). j-outer/k-inner makes weight reads
// contiguous for wide s_load. All per-thread arrays scalar float with
// constant indices after forced full unrolls -> SROA promotes.
// No LDS, no barriers. Grid-limited to 1 wave/SIMD, so VGPR<=512 is free.

namespace {

constexpr int T = 28;
constexpr int I = 28;
constexpr int H = 64;
constexpr int C = 10;

__device__ __forceinline__ float fast_tanh(float xx) {
    // tanh(x) = 1 - 2/(exp(2x)+1); saturates correctly at +-1.
    float e = __expf(2.0f * xx);
    float r = __builtin_amdgcn_rcpf(e + 1.0f);
    return fmaf(-2.0f, r, 1.0f);
}

__global__ __launch_bounds__(256, 1) void rnn_fused(
    const float* __restrict__ x,
    const float* __restrict__ W_ih,   // [H][I] row-major
    const float* __restrict__ W_hh,   // [H][H] row-major
    const float* __restrict__ b_ih,   // [H]
    const float* __restrict__ b_hh,   // [H]
    const float* __restrict__ fc_w,   // [C][H] row-major
    const float* __restrict__ fc_b,   // [C]
    float* __restrict__ out,          // [B][C]
    int nB)
{
    const int s = blockIdx.x * blockDim.x + threadIdx.x;
    if (s >= nB) return;
    const float* __restrict__ xrow = x + (size_t)s * (T * I);

    float h[H], hn[H], xc[I], xn[I];

    // ---- load x_0, prefetch x_1 (float4, coalesced) ----
    #pragma unroll 7
    for (int q = 0; q < 7; ++q) {
        const float4 v = *reinterpret_cast<const float4*>(xrow + 4 * q);
        xc[4 * q + 0] = v.x; xc[4 * q + 1] = v.y;
        xc[4 * q + 2] = v.z; xc[4 * q + 3] = v.w;
    }
    #pragma unroll 7
    for (int q = 0; q < 7; ++q) {
        const float4 v = *reinterpret_cast<const float4*>(xrow + I + 4 * q);
        xn[4 * q + 0] = v.x; xn[4 * q + 1] = v.y;
        xn[4 * q + 2] = v.z; xn[4 * q + 3] = v.w;
    }

    // ---- t = 0: h = tanh(x_0 @ W_ih^T + b); h0 == 0 ----
    #pragma unroll 64
    for (int j = 0; j < H; ++j) {
        float a0 = b_ih[j] + b_hh[j];   // uniform -> scalar loads/adds
        float a1 = 0.0f;
        #pragma unroll 14
        for (int i2 = 0; i2 < I / 2; ++i2) {
            a0 = fmaf(xc[2 * i2 + 0], W_ih[j * I + 2 * i2 + 0], a0);
            a1 = fmaf(xc[2 * i2 + 1], W_ih[j * I + 2 * i2 + 1], a1);
        }
        h[j] = fast_tanh(a0 + a1);
    }

    // ---- t = 1 .. T-1 ----
    for (int t = 1; t < T; ++t) {
        // x_t comes from the prefetch buffer
        #pragma unroll 28
        for (int i = 0; i < I; ++i) xc[i] = xn[i];
        // issue prefetch of x_{t+1}; consumed next iteration, hides under FMAs
        const int tn = (t + 1 < T) ? t + 1 : t;
        #pragma unroll 7
        for (int q = 0; q < 7; ++q) {
            const float4 v = *reinterpret_cast<const float4*>(xrow + tn * I + 4 * q);
            xn[4 * q + 0] = v.x; xn[4 * q + 1] = v.y;
            xn[4 * q + 2] = v.z; xn[4 * q + 3] = v.w;
        }

        #pragma unroll 64
        for (int j = 0; j < H; ++j) {
            float a0 = b_ih[j] + b_hh[j];
            float a1 = 0.0f;
            #pragma unroll 14
            for (int i2 = 0; i2 < I / 2; ++i2) {
                a0 = fmaf(xc[2 * i2 + 0], W_ih[j * I + 2 * i2 + 0], a0);
                a1 = fmaf(xc[2 * i2 + 1], W_ih[j * I + 2 * i2 + 1], a1);
            }
            #pragma unroll 32
            for (int k2 = 0; k2 < H / 2; ++k2) {
                a0 = fmaf(h[2 * k2 + 0], W_hh[j * H + 2 * k2 + 0], a0);
                a1 = fmaf(h[2 * k2 + 1], W_hh[j * H + 2 * k2 + 1], a1);
            }
            hn[j] = fast_tanh(a0 + a1);
        }
        #pragma unroll 64
        for (int j = 0; j < H; ++j) h[j] = hn[j];
    }

    // ---- FC + softmax ----
    float logits[C];
    #pragma unroll 10
    for (int c = 0; c < C; ++c) {
        float a0 = fc_b[c];
        float a1 = 0.0f;
        #pragma unroll 32
        for (int k2 = 0; k2 < H / 2; ++k2) {
            a0 = fmaf(h[2 * k2 + 0], fc_w[c * H + 2 * k2 + 0], a0);
            a1 = fmaf(h[2 * k2 + 1], fc_w[c * H + 2 * k2 + 1], a1);
        }
        logits[c] = a0 + a1;
    }
    float m = logits[0];
    #pragma unroll 9
    for (int c = 1; c < C; ++c) m = fmaxf(m, logits[c]);
    float sum = 0.0f;
    #pragma unroll 10
    for (int c = 0; c < C; ++c) {
        const float e = __expf(logits[c] - m);
        logits[c] = e;
        sum += e;
    }
    float r = __builtin_amdgcn_rcpf(sum);
    r = r * (2.0f - sum * r);               // one Newton step
    float2* o2 = reinterpret_cast<float2*>(out + (size_t)s * C);
    #pragma unroll 5
    for (int p = 0; p < 5; ++p) {
        float2 v;
        v.x = logits[2 * p + 0] * r;
        v.y = logits[2 * p + 1] * r;
        o2[p] = v;
    }
}

} // namespace

extern "C" void kernel_launch(void* const* d_in, const int* in_sizes, int n_in,
                              void* d_out, int out_size, void* d_ws, size_t ws_size,
                              hipStream_t stream) {
    const float* x    = (const float*)d_in[0];
    const float* W_ih = (const float*)d_in[1];
    const float* W_hh = (const float*)d_in[2];
    const float* b_ih = (const float*)d_in[3];
    const float* b_hh = (const float*)d_in[4];
    const float* fc_w = (const float*)d_in[5];
    const float* fc_b = (const float*)d_in[6];
    float* out = (float*)d_out;

    const int nB = in_sizes[0] / (T * I);   // 65536
    const int block = 256;
    const int grid = (nB + block - 1) / block;
    rnn_fused<<<grid, block, 0, stream>>>(x, W_ih, W_hh, b_ih, b_hh, fc_w, fc_b, out, nB);
}

// Round 6
// 325.242 us; speedup vs baseline: 57.0731x; 2.7582x over previous
//
#include <hip/hip_runtime.h>

// Fused tanh-RNN: x[B,784] -> softmax(FC(h_T)), B=65536, T=28, I=28, H=64, C=10.
// Round 5 resubmit (round-5 bench never acquired a GPU; kernel unchanged).
// MFMA wave-GEMM. Each wave owns 32 samples. Per step t:
//     D'[j][m] = sum_k W_hh[j][k] h_t[k][m] + sum_i W_ih[j][i] x_t[m][i] + b[j]
// via v_mfma_f32_32x32x16_f16, A = weights (M=j, static, preloaded in VGPRs),
// B = h^T / x^T (N=32 samples on lanes). Bias enters through the K-padding
// slot i=28 (A=b, B=1). h recycles D'->B-frag in-register via cvt_pk + shfl_xor(32)
// (T12 pattern) -- no LDS, no barriers. fp16 operands, fp32 MFMA accumulate.
// K-permutation invariance: A and B built with the SAME lane->k map, so the
// contraction is correct for any HW k-order; only the D layout (HW-verified:
// col=lane&31, row=(r&3)+8*(r>>2)+4*(lane>>5)) and A-row/B-col=lane&31 matter.

namespace {

constexpr int T = 28;
constexpr int I = 28;
constexpr int H = 64;
constexpr int C = 10;

typedef _Float16 half8 __attribute__((ext_vector_type(8)));
typedef _Float16 half2v __attribute__((ext_vector_type(2)));
typedef float f32x16 __attribute__((ext_vector_type(16)));
typedef unsigned int u32;
typedef u32 u32x4 __attribute__((ext_vector_type(4)));

__device__ __forceinline__ u32 pkh(float a, float b) {
    half2v t; t[0] = (_Float16)a; t[1] = (_Float16)b;   // lo = smaller k
    return __builtin_bit_cast(u32, t);
}
__device__ __forceinline__ half8 mk8(u32 w0, u32 w1, u32 w2, u32 w3) {
    u32x4 v; v[0] = w0; v[1] = w1; v[2] = w2; v[3] = w3;
    return __builtin_bit_cast(half8, v);
}
__device__ __forceinline__ float fast_tanh(float xx) {
    float e = __expf(2.0f * xx);
    float r = __builtin_amdgcn_rcpf(e + 1.0f);
    return fmaf(-2.0f, r, 1.0f);
}

#define MFMA(A, B, Cc) __builtin_amdgcn_mfma_f32_32x32x16_f16((A), (B), (Cc), 0, 0, 0)

// Build next-step B-fragment (one 16-k block) from tanh'd D regs HF[ro..ro+7].
// Derivation (D row j = (r&3)+8*(r>>2)+4*hi, B k-slot = 8*hi+ii):
//   hi=0 lanes need j 0..7 of the octet = [pk(r0,r1), pk(r2,r3)] local + same from hi=1
//   hi=1 lanes need j 8..15            = [pk(r4,r5), pk(r6,r7)] from hi=0 + local
#define BUILD_BH(dst, HF, ro)                                              \
    {                                                                      \
        const u32 a0 = pkh(HF[(ro) + 0], HF[(ro) + 1]);                    \
        const u32 a1 = pkh(HF[(ro) + 2], HF[(ro) + 3]);                    \
        const u32 a2 = pkh(HF[(ro) + 4], HF[(ro) + 5]);                    \
        const u32 a3 = pkh(HF[(ro) + 6], HF[(ro) + 7]);                    \
        const u32 s0 = __shfl_xor(a0, 32, 64);                             \
        const u32 s1 = __shfl_xor(a1, 32, 64);                             \
        const u32 s2 = __shfl_xor(a2, 32, 64);                             \
        const u32 s3 = __shfl_xor(a3, 32, 64);                             \
        dst = mk8(hi ? s2 : a0, hi ? s3 : a1, hi ? a2 : s0, hi ? a3 : s1); \
    }

__global__ __launch_bounds__(256, 2) void rnn_mfma(
    const float* __restrict__ x,
    const float* __restrict__ W_ih,   // [H][I]
    const float* __restrict__ W_hh,   // [H][H]
    const float* __restrict__ b_ih,   // [H]
    const float* __restrict__ b_hh,   // [H]
    const float* __restrict__ fc_w,   // [C][H]
    const float* __restrict__ fc_b,   // [C]
    float* __restrict__ out)          // [B][C]
{
    const int lane = threadIdx.x & 63;
    const int hi   = lane >> 5;
    const int p    = lane & 31;                      // A-row j_local / sample col m
    const int wave = (blockIdx.x << 2) + (threadIdx.x >> 6);
    const int sample = (wave << 5) + p;

    // ---------- one-time: weight A-fragments (fp16), static in VGPRs ----------
    half8 Ahh[2][4];                                 // [jtile][kblock]
    #pragma unroll
    for (int Tt = 0; Tt < 2; ++Tt) {
        #pragma unroll
        for (int kb = 0; kb < 4; ++kb) {
            const float* wr = W_hh + (Tt * 32 + p) * H + kb * 16 + hi * 8;
            const float4 f0 = *(const float4*)(wr);
            const float4 f1 = *(const float4*)(wr + 4);
            Ahh[Tt][kb] = mk8(pkh(f0.x, f0.y), pkh(f0.z, f0.w),
                              pkh(f1.x, f1.y), pkh(f1.z, f1.w));
        }
    }
    half8 Aih[2][2];
    #pragma unroll
    for (int Tt = 0; Tt < 2; ++Tt) {
        const int j = Tt * 32 + p;
        const float* wr = W_ih + j * I;
        {   // kb=0: i = 8*hi + ii, 0..15 all valid
            const float4 f0 = *(const float4*)(wr + 8 * hi);
            const float4 f1 = *(const float4*)(wr + 8 * hi + 4);
            Aih[Tt][0] = mk8(pkh(f0.x, f0.y), pkh(f0.z, f0.w),
                             pkh(f1.x, f1.y), pkh(f1.z, f1.w));
        }
        if (hi == 0) {   // kb=1: i = 16..23
            const float4 f0 = *(const float4*)(wr + 16);
            const float4 f1 = *(const float4*)(wr + 20);
            Aih[Tt][1] = mk8(pkh(f0.x, f0.y), pkh(f0.z, f0.w),
                             pkh(f1.x, f1.y), pkh(f1.z, f1.w));
        } else {         // kb=1: i = 24..27, then bias slot (i=28), zeros
            const float4 f0 = *(const float4*)(wr + 24);
            const float bj = b_ih[j] + b_hh[j];
            Aih[Tt][1] = mk8(pkh(f0.x, f0.y), pkh(f0.z, f0.w), pkh(bj, 0.0f), 0u);
        }
    }

    const float* __restrict__ xrow = x + (size_t)sample * (T * I);
    const u32 ONEH = 0x00003C00u;                    // fp16 pair {1.0, 0.0}

    // x slice prefetch registers; per step a lane needs x[m][kb*16 + 8*hi + ii].
    // hi=1 kb=1 covers i=24..27 only (i=28 is the bias slot) -> dup-load, ignore.
    float4 xf0, xf1, xf2, xf3;
    {
        const int o0 = 8 * hi;
        xf0 = *(const float4*)(xrow + o0);
        xf1 = *(const float4*)(xrow + o0 + 4);
        const int o2 = 16 + 8 * hi;
        xf2 = *(const float4*)(xrow + o2);
        xf3 = *(const float4*)(xrow + o2 + (hi ? 0 : 4));
    }

    f32x16 ZERO;
    #pragma unroll
    for (int e = 0; e < 16; ++e) ZERO[e] = 0.0f;

    f32x16 hf0, hf1;   // tanh'd hidden state in D-layout (fp32)

    // ---------- t = 0 (h0 = 0: x-projection + bias only) ----------
    {
        half8 Bx0 = mk8(pkh(xf0.x, xf0.y), pkh(xf0.z, xf0.w),
                        pkh(xf1.x, xf1.y), pkh(xf1.z, xf1.w));
        const u32 xw2 = hi ? ONEH : pkh(xf3.x, xf3.y);
        const u32 xw3 = hi ? 0u   : pkh(xf3.z, xf3.w);
        half8 Bx1 = mk8(pkh(xf2.x, xf2.y), pkh(xf2.z, xf2.w), xw2, xw3);

        {   // prefetch t=1
            const int b = I;
            const int o0 = b + 8 * hi;
            xf0 = *(const float4*)(xrow + o0);
            xf1 = *(const float4*)(xrow + o0 + 4);
            const int o2 = b + 16 + 8 * hi;
            xf2 = *(const float4*)(xrow + o2);
            xf3 = *(const float4*)(xrow + o2 + (hi ? 0 : 4));
        }

        f32x16 D0 = MFMA(Aih[0][0], Bx0, ZERO);
        D0 = MFMA(Aih[0][1], Bx1, D0);
        f32x16 D1 = MFMA(Aih[1][0], Bx0, ZERO);
        D1 = MFMA(Aih[1][1], Bx1, D1);
        #pragma unroll
        for (int e = 0; e < 16; ++e) { hf0[e] = fast_tanh(D0[e]); hf1[e] = fast_tanh(D1[e]); }
    }

    // ---------- t = 1 .. T-1 ----------
    for (int t = 1; t < T; ++t) {
        // h -> B fragments (k blocks 0..3 = hidden units 0..63)
        half8 Bh0, Bh1, Bh2, Bh3;
        BUILD_BH(Bh0, hf0, 0)
        BUILD_BH(Bh1, hf0, 8)
        BUILD_BH(Bh2, hf1, 0)
        BUILD_BH(Bh3, hf1, 8)

        // x fragment for this step (prefetched last iteration)
        half8 Bx0 = mk8(pkh(xf0.x, xf0.y), pkh(xf0.z, xf0.w),
                        pkh(xf1.x, xf1.y), pkh(xf1.z, xf1.w));
        const u32 xw2 = hi ? ONEH : pkh(xf3.x, xf3.y);
        const u32 xw3 = hi ? 0u   : pkh(xf3.z, xf3.w);
        half8 Bx1 = mk8(pkh(xf2.x, xf2.y), pkh(xf2.z, xf2.w), xw2, xw3);

        {   // prefetch next step's x (clamped; dup-read at t=27 is discarded)
            const int tn = (t + 1 < T) ? t + 1 : t;
            const int b = tn * I;
            const int o0 = b + 8 * hi;
            xf0 = *(const float4*)(xrow + o0);
            xf1 = *(const float4*)(xrow + o0 + 4);
            const int o2 = b + 16 + 8 * hi;
            xf2 = *(const float4*)(xrow + o2);
            xf3 = *(const float4*)(xrow + o2 + (hi ? 0 : 4));
        }

        f32x16 D0 = MFMA(Aih[0][0], Bx0, ZERO);
        D0 = MFMA(Aih[0][1], Bx1, D0);
        D0 = MFMA(Ahh[0][0], Bh0, D0);
        D0 = MFMA(Ahh[0][1], Bh1, D0);
        D0 = MFMA(Ahh[0][2], Bh2, D0);
        D0 = MFMA(Ahh[0][3], Bh3, D0);
        f32x16 D1 = MFMA(Aih[1][0], Bx0, ZERO);
        D1 = MFMA(Aih[1][1], Bx1, D1);
        D1 = MFMA(Ahh[1][0], Bh0, D1);
        D1 = MFMA(Ahh[1][1], Bh1, D1);
        D1 = MFMA(Ahh[1][2], Bh2, D1);
        D1 = MFMA(Ahh[1][3], Bh3, D1);
        #pragma unroll
        for (int e = 0; e < 16; ++e) { hf0[e] = fast_tanh(D0[e]); hf1[e] = fast_tanh(D1[e]); }
    }

    // ---------- FC + softmax ----------
    // lane (hi,m) holds h[j] for j = Tt*32 + (r&3)+8*(r>>2) + 4*hi.
    float pl[C];
    #pragma unroll
    for (int c = 0; c < C; ++c) {
        float acc = 0.0f;
        #pragma unroll
        for (int r = 0; r < 16; ++r) {
            const int jb = (r & 3) + 8 * (r >> 2);
            const float w0a = fc_w[c * H + jb];          // uniform -> s_load
            const float w1a = fc_w[c * H + jb + 4];
            acc = fmaf(hf0[r], hi ? w1a : w0a, acc);
            const float w0b = fc_w[c * H + 32 + jb];
            const float w1b = fc_w[c * H + 32 + jb + 4];
            acc = fmaf(hf1[r], hi ? w1b : w0b, acc);
        }
        pl[c] = acc;
    }
    float lg[C];
    #pragma unroll
    for (int c = 0; c < C; ++c)
        lg[c] = pl[c] + __shfl_xor(pl[c], 32, 64) + fc_b[c];

    float mx = lg[0];
    #pragma unroll
    for (int c = 1; c < C; ++c) mx = fmaxf(mx, lg[c]);
    float sum = 0.0f;
    #pragma unroll
    for (int c = 0; c < C; ++c) {
        const float e = __expf(lg[c] - mx);
        lg[c] = e;
        sum += e;
    }
    float rs = __builtin_amdgcn_rcpf(sum);
    rs = rs * (2.0f - sum * rs);                     // Newton step

    if (hi == 0) {
        float2* o2 = reinterpret_cast<float2*>(out + (size_t)sample * C);
        #pragma unroll
        for (int q = 0; q < 5; ++q) {
            float2 v;
            v.x = lg[2 * q + 0] * rs;
            v.y = lg[2 * q + 1] * rs;
            o2[q] = v;
        }
    }
}

} // namespace

extern "C" void kernel_launch(void* const* d_in, const int* in_sizes, int n_in,
                              void* d_out, int out_size, void* d_ws, size_t ws_size,
                              hipStream_t stream) {
    const float* x    = (const float*)d_in[0];
    const float* W_ih = (const float*)d_in[1];
    const float* W_hh = (const float*)d_in[2];
    const float* b_ih = (const float*)d_in[3];
    const float* b_hh = (const float*)d_in[4];
    const float* fc_w = (const float*)d_in[5];
    const float* fc_b = (const float*)d_in[6];
    float* out = (float*)d_out;

    const int nB = in_sizes[0] / (T * I);            // 65536
    const int blocks = nB / 128;                     // 4 waves x 32 samples per block
    rnn_mfma<<<blocks, 256, 0, stream>>>(x, W_ih, W_hh, b_ih, b_hh, fc_w, fc_b, out);
}

// Round 9
// 305.722 us; speedup vs baseline: 60.7169x; 1.0638x over previous
//
#include <hip/hip_runtime.h>

// Fused tanh-RNN: x[B,784] -> softmax(FC(h_T)), B=65536, T=28, I=28, H=64, C=10.
// Round 7 kernel, third submission (rounds 7 and 8 both lost to GPU-broker
// timeouts; kernel unchanged so counters map 1:1 onto the standing prediction).
// 16x16x32 f16 MFMA, 16 samples/wave -> 4096 waves = 4 waves/SIMD (2x TLP
// vs round 6). Custom h-unit<->k-slot bijection u(kb,lg,e)=(2kb+(e>>2))*16+lg*4+(e&3)
// (legal because A and B share the HW k-map; validated empirically in round 6) makes
// the D->next-B repack PURE REGISTER PACKING: zero cross-lane ops in the recurrence.
// Weights static in VGPR A-frags; bias via K-pad slot i=28; FC = 2 MFMAs (C padded
// to 16); softmax via 2 shfl_xor over the 4-lane sample quad. No LDS, no barriers.

namespace {

constexpr int T = 28;
constexpr int I = 28;
constexpr int H = 64;
constexpr int C = 10;

typedef _Float16 half8 __attribute__((ext_vector_type(8)));
typedef _Float16 half2v __attribute__((ext_vector_type(2)));
typedef float f32x4 __attribute__((ext_vector_type(4)));
typedef unsigned int u32;
typedef u32 u32x4 __attribute__((ext_vector_type(4)));

__device__ __forceinline__ u32 pkh(float a, float b) {
    half2v t; t[0] = (_Float16)a; t[1] = (_Float16)b;
    return __builtin_bit_cast(u32, t);
}
__device__ __forceinline__ half8 mk8(u32 a, u32 b, u32 c, u32 d) {
    u32x4 v; v[0] = a; v[1] = b; v[2] = c; v[3] = d;
    return __builtin_bit_cast(half8, v);
}
__device__ __forceinline__ float fast_tanh(float xx) {
    float e = __expf(2.0f * xx);
    float r = __builtin_amdgcn_rcpf(e + 1.0f);
    return fmaf(-2.0f, r, 1.0f);
}

#define MFMA16(A, B, Cc) __builtin_amdgcn_mfma_f32_16x16x32_f16((A), (B), (Cc), 0, 0, 0)

__global__ __launch_bounds__(256, 4) void rnn_mfma16(
    const float* __restrict__ x,
    const float* __restrict__ W_ih,   // [H][I]
    const float* __restrict__ W_hh,   // [H][H]
    const float* __restrict__ b_ih,   // [H]
    const float* __restrict__ b_hh,   // [H]
    const float* __restrict__ fc_w,   // [C][H]
    const float* __restrict__ fc_b,   // [C]
    float* __restrict__ out)          // [B][C]
{
    const int lane = threadIdx.x & 63;
    const int lg   = lane >> 4;                       // k-group 0..3
    const int sc   = lane & 15;                       // sample col / A row
    const int wave = (blockIdx.x << 2) + (threadIdx.x >> 6);
    const int sample = (wave << 4) + sc;

    // ---------- one-time weight A-fragments (fp16, static in VGPRs) ----------
    // k-map (shared by all A and B frags): u(kb,lg,e) = (2kb+(e>>2))*16 + lg*4 + (e&3)
    half8 Ahh[4][2];                                  // [jtile][kblock]
    #pragma unroll
    for (int jt = 0; jt < 4; ++jt) {
        const float* wr = W_hh + (size_t)(jt * 16 + sc) * H;
        #pragma unroll
        for (int kb = 0; kb < 2; ++kb) {
            const float4 qa = *(const float4*)(wr + (2 * kb) * 16 + lg * 4);
            const float4 qb = *(const float4*)(wr + (2 * kb + 1) * 16 + lg * 4);
            Ahh[jt][kb] = mk8(pkh(qa.x, qa.y), pkh(qa.z, qa.w),
                              pkh(qb.x, qb.y), pkh(qb.z, qb.w));
        }
    }
    // x-proj A-frag: k slot (lg,e) -> i = lg*8+e; (3,4)=bias; (3,5..7)=0
    half8 Aih[4];
    #pragma unroll
    for (int jt = 0; jt < 4; ++jt) {
        const int j = jt * 16 + sc;
        const float* wr = W_ih + (size_t)j * I;
        const float4 qa = *(const float4*)(wr + lg * 8);   // lg=3 -> cols 24..27
        u32 w2, w3;
        if (lg < 3) {
            const float4 qb = *(const float4*)(wr + lg * 8 + 4);
            w2 = pkh(qb.x, qb.y); w3 = pkh(qb.z, qb.w);
        } else {
            const float bj = b_ih[j] + b_hh[j];
            w2 = pkh(bj, 0.0f); w3 = 0u;
        }
        Aih[jt] = mk8(pkh(qa.x, qa.y), pkh(qa.z, qa.w), w2, w3);
    }

    const float* __restrict__ xrow = x + (size_t)sample * (T * I);

    // x slice: lane needs floats [lg*8, lg*8+8) of the 28-float strip (lg=3: 24..27+bias)
    float4 xa, xb;
    xa = *(const float4*)(xrow + lg * 8);
    if (lg < 3) xb = *(const float4*)(xrow + lg * 8 + 4);

    u32 pk01[4], pk23[4];                             // packed tanh'd h (B-frag words)
    f32x4 Z4; Z4[0] = 0.0f; Z4[1] = 0.0f; Z4[2] = 0.0f; Z4[3] = 0.0f;
    const u32 ONEH = 0x00003C00u;                     // fp16 {1.0, 0.0}

    // ---------- t = 0 (h0 = 0: x-projection + bias only) ----------
    {
        const u32 w2 = (lg < 3) ? pkh(xb.x, xb.y) : ONEH;
        const u32 w3 = (lg < 3) ? pkh(xb.z, xb.w) : 0u;
        const half8 Bx = mk8(pkh(xa.x, xa.y), pkh(xa.z, xa.w), w2, w3);
        // prefetch t=1
        xa = *(const float4*)(xrow + I + lg * 8);
        if (lg < 3) xb = *(const float4*)(xrow + I + lg * 8 + 4);

        f32x4 D[4];
        #pragma unroll
        for (int jt = 0; jt < 4; ++jt) D[jt] = MFMA16(Aih[jt], Bx, Z4);
        #pragma unroll
        for (int jt = 0; jt < 4; ++jt) {
            const float t0 = fast_tanh(D[jt][0]), t1 = fast_tanh(D[jt][1]);
            const float t2 = fast_tanh(D[jt][2]), t3 = fast_tanh(D[jt][3]);
            pk01[jt] = pkh(t0, t1); pk23[jt] = pkh(t2, t3);
        }
    }

    // ---------- t = 1 .. T-1 ----------
    for (int t = 1; t < T; ++t) {
        const u32 w2 = (lg < 3) ? pkh(xb.x, xb.y) : ONEH;
        const u32 w3 = (lg < 3) ? pkh(xb.z, xb.w) : 0u;
        const half8 Bx = mk8(pkh(xa.x, xa.y), pkh(xa.z, xa.w), w2, w3);

        // prefetch next step's x (clamped dup-read at t=27, discarded)
        const int tn = (t + 1 < T) ? t + 1 : t;
        xa = *(const float4*)(xrow + tn * I + lg * 8);
        if (lg < 3) xb = *(const float4*)(xrow + tn * I + lg * 8 + 4);

        // h B-frags: pure register re-arrangement (zero cross-lane!)
        const half8 Bh0 = mk8(pk01[0], pk23[0], pk01[1], pk23[1]);
        const half8 Bh1 = mk8(pk01[2], pk23[2], pk01[3], pk23[3]);

        f32x4 D[4];
        #pragma unroll
        for (int jt = 0; jt < 4; ++jt) {
            f32x4 d = MFMA16(Aih[jt], Bx, Z4);
            d = MFMA16(Ahh[jt][0], Bh0, d);
            d = MFMA16(Ahh[jt][1], Bh1, d);
            D[jt] = d;
        }
        #pragma unroll
        for (int jt = 0; jt < 4; ++jt) {
            const float t0 = fast_tanh(D[jt][0]), t1 = fast_tanh(D[jt][1]);
            const float t2 = fast_tanh(D[jt][2]), t3 = fast_tanh(D[jt][3]);
            pk01[jt] = pkh(t0, t1); pk23[jt] = pkh(t2, t3);
        }
    }

    // ---------- FC via MFMA (classes padded to 16), same k-map ----------
    half8 Afc[2];
    {
        const int crow = (sc < C) ? sc : (C - 1);     // clamp to avoid OOB
        const float* wr = fc_w + (size_t)crow * H;
        #pragma unroll
        for (int kb = 0; kb < 2; ++kb) {
            const float4 qa = *(const float4*)(wr + (2 * kb) * 16 + lg * 4);
            const float4 qb = *(const float4*)(wr + (2 * kb + 1) * 16 + lg * 4);
            Afc[kb] = mk8(pkh(qa.x, qa.y), pkh(qa.z, qa.w),
                          pkh(qb.x, qb.y), pkh(qb.z, qb.w));
        }
    }
    const half8 Bh0 = mk8(pk01[0], pk23[0], pk01[1], pk23[1]);
    const half8 Bh1 = mk8(pk01[2], pk23[2], pk01[3], pk23[3]);
    f32x4 L = MFMA16(Afc[0], Bh0, Z4);
    L = MFMA16(Afc[1], Bh1, L);
    // lane holds logits[c][sample], c = lg*4 + r (c >= 10 invalid)

    float fb[4];
    #pragma unroll
    for (int r = 0; r < 4; ++r) {
        const float v0 = fc_b[r];
        const float v4 = fc_b[4 + r];
        const float v8 = (r < 2) ? fc_b[8 + r] : 0.0f;
        fb[r] = (lg == 0) ? v0 : (lg == 1) ? v4 : (lg == 2) ? v8 : 0.0f;
    }

    float lr[4];
    float mx = -1e30f;
    #pragma unroll
    for (int r = 0; r < 4; ++r) {
        lr[r] = L[r] + fb[r];
        if (lg * 4 + r < C) mx = fmaxf(mx, lr[r]);
    }
    mx = fmaxf(mx, __shfl_xor(mx, 16, 64));
    mx = fmaxf(mx, __shfl_xor(mx, 32, 64));

    float ex[4];
    float sum = 0.0f;
    #pragma unroll
    for (int r = 0; r < 4; ++r) {
        ex[r] = (lg * 4 + r < C) ? __expf(lr[r] - mx) : 0.0f;
        sum += ex[r];
    }
    sum += __shfl_xor(sum, 16, 64);
    sum += __shfl_xor(sum, 32, 64);
    float rs = __builtin_amdgcn_rcpf(sum);
    rs = rs * (2.0f - sum * rs);                      // Newton step

    float* orow = out + (size_t)sample * C;
    if (lg < 2) {                                     // c = 0..7
        float2 v0; v0.x = ex[0] * rs; v0.y = ex[1] * rs;
        float2 v1; v1.x = ex[2] * rs; v1.y = ex[3] * rs;
        *(float2*)(orow + lg * 4)     = v0;           // byte 40s+16lg   (8B aligned)
        *(float2*)(orow + lg * 4 + 2) = v1;
    } else if (lg == 2) {                             // c = 8,9
        float2 v0; v0.x = ex[0] * rs; v0.y = ex[1] * rs;
        *(float2*)(orow + 8) = v0;                    // byte 40s+32     (8B aligned)
    }
}

} // namespace

extern "C" void kernel_launch(void* const* d_in, const int* in_sizes, int n_in,
                              void* d_out, int out_size, void* d_ws, size_t ws_size,
                              hipStream_t stream) {
    const float* x    = (const float*)d_in[0];
    const float* W_ih = (const float*)d_in[1];
    const float* W_hh = (const float*)d_in[2];
    const float* b_ih = (const float*)d_in[3];
    const float* b_hh = (const float*)d_in[4];
    const float* fc_w = (const float*)d_in[5];
    const float* fc_b = (const float*)d_in[6];
    float* out = (float*)d_out;

    const int nB = in_sizes[0] / (T * I);             // 65536
    const int blocks = nB / 64;                       // 4 waves x 16 samples per block
    rnn_mfma16<<<blocks, 256, 0, stream>>>(x, W_ih, W_hh, b_ih, b_hh, fc_w, fc_b, out);
}

// Round 10
// 305.719 us; speedup vs baseline: 60.7176x; 1.0000x over previous
//
#include <hip/hip_runtime.h>

// Fused tanh-RNN: x[B,784] -> softmax(FC(h_T)), B=65536, T=28, I=28, H=64, C=10.
// Round 10: round-7 structure (16x16x32 f16 MFMA, 16 samples/wave, 4 waves/SIMD,
// zero-shuffle h recycle -- k-map validated by rounds 6/9 passing) + DEPTH-2 x
// PREFETCH: two named x register sets, t-loop unrolled by 2, each x[t] load issued
// two steps ahead (~1440 real cycles > ~900 cyc worst-case scattered-load latency;
// depth-1's ~720 was marginal -- inferred kernel ~100us, VALUBusy-starved).
// Loads beyond T are skipped entirely (no clamp dup-reads).

namespace {

constexpr int T = 28;
constexpr int I = 28;
constexpr int H = 64;
constexpr int C = 10;

typedef _Float16 half8 __attribute__((ext_vector_type(8)));
typedef _Float16 half2v __attribute__((ext_vector_type(2)));
typedef float f32x4 __attribute__((ext_vector_type(4)));
typedef unsigned int u32;
typedef u32 u32x4 __attribute__((ext_vector_type(4)));

__device__ __forceinline__ u32 pkh(float a, float b) {
    half2v t; t[0] = (_Float16)a; t[1] = (_Float16)b;
    return __builtin_bit_cast(u32, t);
}
__device__ __forceinline__ half8 mk8(u32 a, u32 b, u32 c, u32 d) {
    u32x4 v; v[0] = a; v[1] = b; v[2] = c; v[3] = d;
    return __builtin_bit_cast(half8, v);
}
__device__ __forceinline__ float fast_tanh(float xx) {
    float e = __expf(2.0f * xx);
    float r = __builtin_amdgcn_rcpf(e + 1.0f);
    return fmaf(-2.0f, r, 1.0f);
}

#define MFMA16(A, B, Cc) __builtin_amdgcn_mfma_f32_16x16x32_f16((A), (B), (Cc), 0, 0, 0)

// One recurrent step: consume x regs (XA,XB), issue load for step TL into them,
// full 12-MFMA update + tanh + repack. TL >= T skips the load (tail steps).
#define RNN_STEP(XA, XB, TL)                                                  \
    {                                                                         \
        const u32 w2 = (lg < 3) ? pkh(XB.x, XB.y) : ONEH;                     \
        const u32 w3 = (lg < 3) ? pkh(XB.z, XB.w) : 0u;                       \
        const half8 Bx = mk8(pkh(XA.x, XA.y), pkh(XA.z, XA.w), w2, w3);       \
        if ((TL) < T) {                                                       \
            XA = *(const float4*)(xrow + (TL) * I + lg * 8);                  \
            if (lg < 3) XB = *(const float4*)(xrow + (TL) * I + lg * 8 + 4);  \
        }                                                                     \
        const half8 Bh0 = mk8(pk01[0], pk23[0], pk01[1], pk23[1]);            \
        const half8 Bh1 = mk8(pk01[2], pk23[2], pk01[3], pk23[3]);            \
        f32x4 D[4];                                                           \
        _Pragma("unroll")                                                     \
        for (int jt = 0; jt < 4; ++jt) {                                      \
            f32x4 d = MFMA16(Aih[jt], Bx, Z4);                                \
            d = MFMA16(Ahh[jt][0], Bh0, d);                                   \
            d = MFMA16(Ahh[jt][1], Bh1, d);                                   \
            D[jt] = d;                                                        \
        }                                                                     \
        _Pragma("unroll")                                                     \
        for (int jt = 0; jt < 4; ++jt) {                                      \
            const float t0 = fast_tanh(D[jt][0]), t1 = fast_tanh(D[jt][1]);   \
            const float t2 = fast_tanh(D[jt][2]), t3 = fast_tanh(D[jt][3]);   \
            pk01[jt] = pkh(t0, t1); pk23[jt] = pkh(t2, t3);                   \
        }                                                                     \
    }

__global__ __launch_bounds__(256, 4) void rnn_mfma16(
    const float* __restrict__ x,
    const float* __restrict__ W_ih,   // [H][I]
    const float* __restrict__ W_hh,   // [H][H]
    const float* __restrict__ b_ih,   // [H]
    const float* __restrict__ b_hh,   // [H]
    const float* __restrict__ fc_w,   // [C][H]
    const float* __restrict__ fc_b,   // [C]
    float* __restrict__ out)          // [B][C]
{
    const int lane = threadIdx.x & 63;
    const int lg   = lane >> 4;                       // k-group 0..3
    const int sc   = lane & 15;                       // sample col / A row
    const int wave = (blockIdx.x << 2) + (threadIdx.x >> 6);
    const int sample = (wave << 4) + sc;

    // ---------- one-time weight A-fragments (fp16, static in VGPRs) ----------
    // k-map (shared by all A and B frags): u(kb,lg,e) = (2kb+(e>>2))*16 + lg*4 + (e&3)
    half8 Ahh[4][2];                                  // [jtile][kblock]
    #pragma unroll
    for (int jt = 0; jt < 4; ++jt) {
        const float* wr = W_hh + (size_t)(jt * 16 + sc) * H;
        #pragma unroll
        for (int kb = 0; kb < 2; ++kb) {
            const float4 qa = *(const float4*)(wr + (2 * kb) * 16 + lg * 4);
            const float4 qb = *(const float4*)(wr + (2 * kb + 1) * 16 + lg * 4);
            Ahh[jt][kb] = mk8(pkh(qa.x, qa.y), pkh(qa.z, qa.w),
                              pkh(qb.x, qb.y), pkh(qb.z, qb.w));
        }
    }
    // x-proj A-frag: k slot (lg,e) -> i = lg*8+e; (3,4)=bias; (3,5..7)=0
    half8 Aih[4];
    #pragma unroll
    for (int jt = 0; jt < 4; ++jt) {
        const int j = jt * 16 + sc;
        const float* wr = W_ih + (size_t)j * I;
        const float4 qa = *(const float4*)(wr + lg * 8);   // lg=3 -> cols 24..27
        u32 w2, w3;
        if (lg < 3) {
            const float4 qb = *(const float4*)(wr + lg * 8 + 4);
            w2 = pkh(qb.x, qb.y); w3 = pkh(qb.z, qb.w);
        } else {
            const float bj = b_ih[j] + b_hh[j];
            w2 = pkh(bj, 0.0f); w3 = 0u;
        }
        Aih[jt] = mk8(pkh(qa.x, qa.y), pkh(qa.z, qa.w), w2, w3);
    }

    const float* __restrict__ xrow = x + (size_t)sample * (T * I);

    // Depth-2 x prefetch: x0 holds even steps, x1 holds odd steps.
    float4 xa0, xb0, xa1, xb1;
    xa0 = *(const float4*)(xrow + lg * 8);
    if (lg < 3) xb0 = *(const float4*)(xrow + lg * 8 + 4);
    xa1 = *(const float4*)(xrow + I + lg * 8);
    if (lg < 3) xb1 = *(const float4*)(xrow + I + lg * 8 + 4);

    u32 pk01[4], pk23[4];                             // packed tanh'd h (B-frag words)
    f32x4 Z4; Z4[0] = 0.0f; Z4[1] = 0.0f; Z4[2] = 0.0f; Z4[3] = 0.0f;
    const u32 ONEH = 0x00003C00u;                     // fp16 {1.0, 0.0}

    // ---------- t = 0 (h0 = 0: x-projection + bias only); load x[2] -> x0 ----------
    {
        const u32 w2 = (lg < 3) ? pkh(xb0.x, xb0.y) : ONEH;
        const u32 w3 = (lg < 3) ? pkh(xb0.z, xb0.w) : 0u;
        const half8 Bx = mk8(pkh(xa0.x, xa0.y), pkh(xa0.z, xa0.w), w2, w3);
        xa0 = *(const float4*)(xrow + 2 * I + lg * 8);
        if (lg < 3) xb0 = *(const float4*)(xrow + 2 * I + lg * 8 + 4);

        f32x4 D[4];
        #pragma unroll
        for (int jt = 0; jt < 4; ++jt) D[jt] = MFMA16(Aih[jt], Bx, Z4);
        #pragma unroll
        for (int jt = 0; jt < 4; ++jt) {
            const float t0 = fast_tanh(D[jt][0]), t1 = fast_tanh(D[jt][1]);
            const float t2 = fast_tanh(D[jt][2]), t3 = fast_tanh(D[jt][3]);
            pk01[jt] = pkh(t0, t1); pk23[jt] = pkh(t2, t3);
        }
    }

    // ---------- t = 1 .. 26 in pairs (odd consumes x1, even consumes x0) ----------
    for (int t = 1; t + 1 < T; t += 2) {
        RNN_STEP(xa1, xb1, t + 2)     // step t   (odd);  load x[t+2] -> x1
        RNN_STEP(xa0, xb0, t + 3)     // step t+1 (even); load x[t+3] -> x0
    }
    // ---------- t = 27 (odd; no further load) ----------
    RNN_STEP(xa1, xb1, T)

    // ---------- FC via MFMA (classes padded to 16), same k-map ----------
    half8 Afc[2];
    {
        const int crow = (sc < C) ? sc : (C - 1);     // clamp to avoid OOB
        const float* wr = fc_w + (size_t)crow * H;
        #pragma unroll
        for (int kb = 0; kb < 2; ++kb) {
            const float4 qa = *(const float4*)(wr + (2 * kb) * 16 + lg * 4);
            const float4 qb = *(const float4*)(wr + (2 * kb + 1) * 16 + lg * 4);
            Afc[kb] = mk8(pkh(qa.x, qa.y), pkh(qa.z, qa.w),
                          pkh(qb.x, qb.y), pkh(qb.z, qb.w));
        }
    }
    const half8 Bh0 = mk8(pk01[0], pk23[0], pk01[1], pk23[1]);
    const half8 Bh1 = mk8(pk01[2], pk23[2], pk01[3], pk23[3]);
    f32x4 L = MFMA16(Afc[0], Bh0, Z4);
    L = MFMA16(Afc[1], Bh1, L);
    // lane holds logits[c][sample], c = lg*4 + r (c >= 10 invalid)

    float fb[4];
    #pragma unroll
    for (int r = 0; r < 4; ++r) {
        const float v0 = fc_b[r];
        const float v4 = fc_b[4 + r];
        const float v8 = (r < 2) ? fc_b[8 + r] : 0.0f;
        fb[r] = (lg == 0) ? v0 : (lg == 1) ? v4 : (lg == 2) ? v8 : 0.0f;
    }

    float lr[4];
    float mx = -1e30f;
    #pragma unroll
    for (int r = 0; r < 4; ++r) {
        lr[r] = L[r] + fb[r];
        if (lg * 4 + r < C) mx = fmaxf(mx, lr[r]);
    }
    mx = fmaxf(mx, __shfl_xor(mx, 16, 64));
    mx = fmaxf(mx, __shfl_xor(mx, 32, 64));

    float ex[4];
    float sum = 0.0f;
    #pragma unroll
    for (int r = 0; r < 4; ++r) {
        ex[r] = (lg * 4 + r < C) ? __expf(lr[r] - mx) : 0.0f;
        sum += ex[r];
    }
    sum += __shfl_xor(sum, 16, 64);
    sum += __shfl_xor(sum, 32, 64);
    float rs = __builtin_amdgcn_rcpf(sum);
    rs = rs * (2.0f - sum * rs);                      // Newton step

    float* orow = out + (size_t)sample * C;
    if (lg < 2) {                                     // c = 0..7
        float2 v0; v0.x = ex[0] * rs; v0.y = ex[1] * rs;
        float2 v1; v1.x = ex[2] * rs; v1.y = ex[3] * rs;
        *(float2*)(orow + lg * 4)     = v0;
        *(float2*)(orow + lg * 4 + 2) = v1;
    } else if (lg == 2) {                             // c = 8,9
        float2 v0; v0.x = ex[0] * rs; v0.y = ex[1] * rs;
        *(float2*)(orow + 8) = v0;
    }
}

} // namespace

extern "C" void kernel_launch(void* const* d_in, const int* in_sizes, int n_in,
                              void* d_out, int out_size, void* d_ws, size_t ws_size,
                              hipStream_t stream) {
    const float* x    = (const float*)d_in[0];
    const float* W_ih = (const float*)d_in[1];
    const float* W_hh = (const float*)d_in[2];
    const float* b_ih = (const float*)d_in[3];
    const float* b_hh = (const float*)d_in[4];
    const float* fc_w = (const float*)d_in[5];
    const float* fc_b = (const float*)d_in[6];
    float* out = (float*)d_out;

    const int nB = in_sizes[0] / (T * I);             // 65536
    const int blocks = nB / 64;                       // 4 waves x 16 samples per block
    rnn_mfma16<<<blocks, 256, 0, stream>>>(x, W_ih, W_hh, b_ih, b_hh, fc_w, fc_b, out);
}